// Round 9
// baseline (3666.791 us; speedup 1.0000x reference)
//
#include <hip/hip_runtime.h>
#include <hip/hip_bf16.h>
#include <cstdint>
#include <cstddef>

using bf16 = __hip_bfloat16;
typedef __attribute__((ext_vector_type(8))) short   bf16x8_t;  // 8 bf16 (4 VGPRs)
typedef __attribute__((ext_vector_type(4))) float   f32x4_t;   // mfma accumulator

// ---------------- workspace byte offsets ----------------
#define XT_OFF   ((size_t)0)            // [32 wg][256 t][16 r][96] bf16 (coalesced per-wave X)
#define UF_OFF   ((size_t)25165824)     // [336][128] bf16 gate-ordered U strips (fwd)
#define UB_OFF   ((size_t)25251840)     // (bwd)
#define WF_OFF   ((size_t)25337856)     // fwd W shifted: row k -> gru_W[k-1], k=1..64 (K=128 strip)
#define WB_OFF   ((size_t)25423872)     // bwd W: row k -> bgru_W[k], k=0..64
#define DW_OFF   ((size_t)25509888)     // dec_W strips [4][64][256] bf16
#define MW_OFF   ((size_t)25640960)     // mean_W^T strips [4][64][64] bf16
#define SAV_OFF  ((size_t)25673728)     // saved h_back [32 wg][64 slot][16*128] bf16 (8,388,608 B)
#define CST_OFF  ((size_t)34062336)     // fp32: bf0,bf1,bb0,bb1[336 ea], mb[256], db[256]
#define WBF_OFF  ((size_t)34069760)     // frag-linear W tables: [Wb 43008 B][Wf 43008 B]
#define WS_NEED  ((size_t)34155776)

// LDS frag-table bases (permanent)
#define WBF_LDS  63024
#define WFF_LDS  106032
// total LDS = 63024 + 86016 = 149,040 B (<= 160 KiB, 1 WG/CU)

#define MFMA16(a,b,c) __builtin_amdgcn_mfma_f32_16x16x32_bf16((a),(b),(c),0,0,0)

// counted barrier: drain LDS only; global loads/stores stay in flight across it.
#define BAR()    asm volatile("s_waitcnt lgkmcnt(0)\n\ts_barrier" ::: "memory")

// ---------------- prep kernels (fp32 inputs -> bf16 internal) ----------------
__global__ void k_xt(const float* __restrict__ a, bf16* __restrict__ xT){
  int b=blockIdx.x, t=threadIdx.x;
  int wgi=b>>4, r=b&15;
  bf16 buf[96];
  const float* ap = a + (size_t)b*64*256*3;
  #pragma unroll
  for (int c=0;c<64;++c) buf[c] = __float2bfloat16(ap[((size_t)c*256+t)*3]);
  buf[64] = __float2bfloat16(ap[(size_t)t*3 + 2]);
  bf16 z = __float2bfloat16(0.f);
  #pragma unroll
  for (int c=65;c<96;++c) buf[c]=z;
  uint4* dst = (uint4*)(xT + (((size_t)wgi*256 + t)*16 + r)*96);
  const uint4* src = (const uint4*)buf;
  #pragma unroll
  for (int k=0;k<12;++k) dst[k]=src[k];
}

__global__ void k_obs(const float* __restrict__ a, float* __restrict__ out){
  int b=blockIdx.x, d=threadIdx.x; // 64 threads
  for (int kk=0;kk<16;++kk){ int t=kk*16;
    float v = (d<63)? a[(((size_t)b*64 + d+1)*256 + t)*3]
                    : a[((size_t)b*64*256 + t)*3 + 2];
    out[((size_t)b*64 + d)*256 + t] = v;
  }
}

__global__ void k_wt(const float* __restrict__ gru_U, const float* __restrict__ bgru_U,
                     const float* __restrict__ gru_W, const float* __restrict__ bgru_W,
                     bf16* Uf, bf16* Ub, bf16* Wf, bf16* Wb){
  int c=blockIdx.x, k=threadIdx.x; // 336 x 128
  int g=c/48, rm=c%48, e=rm/16, l=rm%16, j=16*g+l;
  bool val = j<100; int gc = val? (e*100+j) : 0;
  bf16 z = __float2bfloat16(0.f);
  Uf[(size_t)c*128+k] = (val&&k<100)? __float2bfloat16(gru_U[k*300+gc]) : z;
  Ub[(size_t)c*128+k] = (val&&k<100)? __float2bfloat16(bgru_U[k*300+gc]) : z;
  Wf[(size_t)c*128+k] = (val&&k>=1&&k<=64)? __float2bfloat16(gru_W[(k-1)*300+gc]) : z;
  Wb[(size_t)c*128+k] = (val&&k<65)? __float2bfloat16(bgru_W[k*300+gc]) : z;
}

// frag-linear copy of W tables (k=0..63, 2 slices): [tbl][strip st][e][s][lane]
__global__ void k_wbf(const bf16* __restrict__ Wb, const bf16* __restrict__ Wf,
                      uint4* __restrict__ dst){
  int bid=blockIdx.x;  // 84: 0..41 Wb, 42..83 Wf
  int l=threadIdx.x;   // 64
  int tbl=bid/42, r2=bid%42;
  int st=r2/6, rr=r2%6, e=rr/2, s=rr%2;
  int c=48*st+16*e+(l&15);
  int k=8*(l>>4)+32*s;
  const bf16* src = tbl? Wf : Wb;
  dst[bid*64+l] = *(const uint4*)(src + (size_t)c*128 + k);
}

__global__ void k_decw(const float* __restrict__ dec_W, bf16* dWt){
  int idx=blockIdx.x; int lvl=idx/64, n=idx%64; int k=threadIdx.x; // 256 blocks x 256 thr
  float v=0.f;
  if (n<50){
    if (k<100) v = dec_W[(lvl*200+k)*50+n];            // h rows 0..99
    else if (k>=128 && k<228) v = dec_W[(lvl*200+k-28)*50+n]; // hb rows 100..199
  }
  dWt[(size_t)idx*256+k] = __float2bfloat16(v);
}

__global__ void k_mw(const float* __restrict__ mean_W, bf16* MW){
  int idx=blockIdx.x; int lvl=idx/64, c=idx%64; int k=threadIdx.x; // 64
  MW[(size_t)idx*64+k] = (k<50)? __float2bfloat16(mean_W[(lvl*50+k)*64+c]) : __float2bfloat16(0.f);
}

__global__ void k_consts(const float* __restrict__ gru_b, const float* __restrict__ bgru_b,
                         const float* __restrict__ mean_b, const float* __restrict__ dec_b,
                         float* cst){
  int tid=threadIdx.x;
  for (int u=tid; u<336; u+=256){
    int c=u; int g=c/48, rm=c%48, e=rm/16, l=rm%16, j=16*g+l;
    float b0f=0,b1f=0,b0b=0,b1b=0;
    if (j<100){ int gc=e*100+j;
      b0f=gru_b[gc];  b1f=gru_b[300+gc];
      b0b=bgru_b[gc]; b1b=bgru_b[300+gc]; }
    cst[u]=b0f; cst[336+u]=b1f; cst[672+u]=b0b; cst[1008+u]=b1b;
  }
  if (tid<256){
    int lvl=tid/64, m=tid%64;
    cst[1344+tid]=mean_b[lvl*64+m];
    cst[1600+tid]=(m<50)? dec_b[lvl*50+m] : 0.f;
  }
}

__global__ void k_sz(uint4* p){
  p[(size_t)blockIdx.x*256 + threadIdx.x] = make_uint4(0u,0u,0u,0u);
}

// ---------------- specialized backward GRU cell (8-wave: 1 strip/wave) ----------------
static __device__ __forceinline__ void bcell_step(
  int t, int bc, int sv,
  unsigned char* smem, const bf16* xT, unsigned char* sav8,
  int wg, int tid, int l15, int q, int wv, bool act,
  const bf16x8_t (&rUb)[3][4], const float (&W64b)[3],
  float Bzb, float Brb, float Bn0b, float Bn1b,
  float (&hb_reg)[4], bf16x8_t (&pX)[2])
{
  const int lane = tid & 63;
  bf16x8_t nX0, nX1;
  f32x4_t accB[3], accA[3];
  if (act){
    const bf16* px = xT + (((size_t)wg*256 + (t-1))*16 + l15)*96 + 8*q;
    nX0 = *(const bf16x8_t*)(px);
    nX1 = *(const bf16x8_t*)(px + 32);
    const bf16* hp = (const bf16*)(smem + 6784) + bc*1696 + l15*104 + 8*q;
    bf16x8_t aH[4];
    #pragma unroll
    for (int s=0;s<4;++s) aH[s] = *(const bf16x8_t*)(hp + 32*s);
    #pragma unroll
    for (int e=0;e<3;++e){
      accB[e]=(f32x4_t){0,0,0,0}; accA[e]=(f32x4_t){0,0,0,0};
      #pragma unroll
      for (int s=0;s<4;++s) accB[e] = MFMA16(aH[s], rUb[e][s], accB[e]);
      const unsigned char* fb = smem + WBF_LDS + (((wv*3+e)*2)<<10) + lane*16;
      accA[e] = MFMA16(pX[0], *(const bf16x8_t*)(fb),      accA[e]);
      accA[e] = MFMA16(pX[1], *(const bf16x8_t*)(fb+1024), accA[e]);
    }
  }
  if (sv>=0 && tid<208){
    int r=tid/13, cc=tid-13*r;
    const uint4 v = *(const uint4*)(smem + 6784 + bc*3392 + r*208 + cc*16);
    *(uint4*)(sav8 + ((size_t)(wg*64+sv))*4096 + (size_t)r*256 + cc*16) = v;
  }
  const bool mk = ((t&15)==0);
  bf16* wr = (bf16*)(smem + 6784) + (bc^1)*1696;
  const int jj = 16*wv + l15;
  if (act && jj<100){
    #pragma unroll
    for (int i=0;i<4;++i){
      int r=4*q+i;
      float gz=accA[0][i], gr=accA[1][i], gn=accA[2][i];
      if (mk){ gz+=W64b[0]; gr+=W64b[1]; gn+=W64b[2]; }
      float hz=accB[0][i], hr=accB[1][i], hnv=accB[2][i];
      float hold = hb_reg[i];
      float az = gz+hz+Bzb;
      float ar = gr+hr+Brb;
      float z  = 1.f/(1.f+__expf(-az));
      float rg = 1.f/(1.f+__expf(-ar));
      float an = gn+Bn0b+rg*(hnv+Bn1b); an=fminf(fmaxf(an,-15.f),15.f);
      float e2 = __expf(2.f*an);
      float nn = (e2-1.f)/(e2+1.f);
      float hnew = z*hold + (1.f-z)*nn;
      hb_reg[i]=hnew;
      wr[r*104+jj] = __float2bfloat16(hnew);
    }
  }
  if (act){ pX[0]=nX0; pX[1]=nX1; }
  BAR();
}

// ---------------- main persistent kernel: 32 WGs x 512 thr (8 waves), 16 batch rows each ----
// Wave wv (0..6) owns gate-column strip j = 16*wv + l15 (j<100); wave 7 idles in cell work.
// 2 waves/SIMD: one wave's LDS/MFMA stalls overlap the co-resident wave's issue.
__launch_bounds__(512, 1)
__global__ void naomi_main(unsigned char* __restrict__ ws, float* __restrict__ out){
  const int tid=threadIdx.x, wg=blockIdx.x;
  const int lane=tid&63, wv=tid>>6;     // 0..7
  const int l15=lane&15, q=lane>>4;
  const bool act=(wv<7);
  const int j = 16*wv + l15;            // owned gate column (valid if act && j<100)
  const bool jv = act && (j<100);

  const bf16* xT = (const bf16*)(ws + XT_OFF);
  const bf16* Uf = (const bf16*)(ws + UF_OFF);
  const bf16* Ub = (const bf16*)(ws + UB_OFF);
  const bf16* Wf = (const bf16*)(ws + WF_OFF);
  const bf16* Wb = (const bf16*)(ws + WB_OFF);
  const bf16* dW = (const bf16*)(ws + DW_OFF);
  const bf16* MW = (const bf16*)(ws + MW_OFF);
  bf16* sav = (bf16*)(ws + SAV_OFF);
  unsigned char* sav8 = (unsigned char*)(ws + SAV_OFF);
  const float* cst = (const float*)(ws + CST_OFF);

  // LDS (149,040 B): s_h 2x[16][104] | s_hbk 2x[16][104] | s_dec [16][72]+pad |
  //   ring [8][16][120] | spl [4][16][104] | Wb frags 43008 | Wf frags 43008
  __shared__ alignas(16) unsigned char smem[149040];
  bf16* s_h    = (bf16*)(smem + 0);      // 6784 B (two 1696-elem buffers)
  bf16* s_hbk  = (bf16*)(smem + 6784);   // 6784 B
  bf16* s_dec  = (bf16*)(smem + 13568);  // 2352 B
  bf16* s_ring = (bf16*)(smem + 15920);  // 30720 B
  bf16* s_spl  = (bf16*)(smem + 46640);  // 13312 B used (+ zeroed slack to 63024)

  for (int u=tid; u<15756; u+=512) ((uint32_t*)smem)[u]=0u;
  { uint4* df=(uint4*)(smem+WBF_LDS); const uint4* sf=(const uint4*)(ws+WBF_OFF);
    for (int u=tid; u<5376; u+=512) df[u]=sf[u]; }

  // per-thread gate biases (z/r biases pre-folded: b0+b1)
  float Bzf,Brf,Bn0f,Bn1f, Bzb,Brb,Bn0b,Bn1b;
  if (act){
    int cz=48*wv+l15;
    Bzf=cst[cz]+cst[336+cz];         Brf=cst[cz+16]+cst[336+cz+16];
    Bn0f=cst[cz+32];                 Bn1f=cst[336+cz+32];
    Bzb=cst[672+cz]+cst[1008+cz];    Brb=cst[672+cz+16]+cst[1008+cz+16];
    Bn0b=cst[672+cz+32];             Bn1b=cst[1008+cz+32];
  } else {
    Bzf=Brf=Bn0f=Bn1f=Bzb=Brb=Bn0b=Bn1b=0.f;
  }
  const int c16 = 16*wv+l15;            // DEC output column (valid wv<4)
  float mb_l[4], db_l[4];
  if (wv<4){
    #pragma unroll
    for (int l=0;l<4;++l){ mb_l[l]=cst[1344+l*64+c16]; db_l[l]=cst[1600+l*64+c16]; }
  } else {
    #pragma unroll
    for (int l=0;l<4;++l){ mb_l[l]=0.f; db_l[l]=0.f; }
  }

  // U strips resident in registers (one strip per wave)
  bf16x8_t rUf[3][4], rUb[3][4];
  if (act){
    #pragma unroll
    for (int e=0;e<3;++e){ int c=48*wv+16*e+l15;
      #pragma unroll
      for (int s=0;s<4;++s)
        rUb[e][s] = *(const bf16x8_t*)(Ub + (size_t)c*128 + 8*q + 32*s);
    }
  }
  float W64b[3], W64f[3];
  if (act){
    #pragma unroll
    for (int e=0;e<3;++e){ int c=48*wv+16*e+l15;
      W64b[e] = __bfloat162float(Wb[(size_t)c*128 + 64]);
      W64f[e] = __bfloat162float(Wf[(size_t)c*128 + 64]); }
  } else {
    W64b[0]=W64b[1]=W64b[2]=0.f; W64f[0]=W64f[1]=W64f[2]=0.f;
  }
  __syncthreads();

  float h_reg[4], hb_reg[4];
  #pragma unroll
  for (int i=0;i<4;++i){ h_reg[i]=0.f; hb_reg[i]=0.f; }
  int hcur=0, bcur=0;

  bf16x8_t pX[2], pHB[4], rS16[4];
  float pHold[4];
  #pragma unroll
  for (int i=0;i<4;++i) pHold[i]=0.f;
  if (act){
    const bf16* px = xT + (((size_t)wg*256 + 255)*16 + l15)*96 + 8*q;
    pX[0] = *(const bf16x8_t*)(px);
    pX[1] = *(const bf16x8_t*)(px + 32);
  }

  // ================= specialized backward sweep: t = 255 .. 1 =================
  bcell_step(255, 0, 63, smem, xT, sav8, wg, tid, l15, q, wv, act,
             rUb, W64b, Bzb,Brb,Bn0b,Bn1b, hb_reg, pX);
  for (int t=254; t>=2; t-=2){
    int m=t&15;
    int sv1 = (m==8)? ((t>>4)<<2) : (m==12)? (((t>>4)<<2)+1) : (m==14)? (((t>>4)<<2)+2) : -1;
    bcell_step(t, 1, sv1, smem, xT, sav8, wg, tid, l15, q, wv, act,
               rUb, W64b, Bzb,Brb,Bn0b,Bn1b, hb_reg, pX);
    int sv2 = (((t-1)&15)==15)? ((((t-1)>>4)<<2)+3) : -1;
    bcell_step(t-1, 0, sv2, smem, xT, sav8, wg, tid, l15, q, wv, act,
               rUb, W64b, Bzb,Brb,Bn0b,Bn1b, hb_reg, pX);
  }
  bcur = 1;   // parity after 255 steps

  // ================= bwd -> fwd transition =================
  if (act){
    #pragma unroll
    for (int e=0;e<3;++e){ int c=48*wv+16*e+l15;
      #pragma unroll
      for (int s=0;s<4;++s)
        rUf[e][s] = *(const bf16x8_t*)(Uf + (size_t)c*128 + 8*q + 32*s);
    }
  }
  __syncthreads();   // full drain: sav stores visible before fwd sav reads

  // ================= straight-line forward phase =================
#define GRU_MATH(BZ,BR,BN0,BN1) \
  float az=gz+hz+(BZ); \
  float ar=gr+hr+(BR); \
  float z_=1.f/(1.f+__expf(-az)); float rg=1.f/(1.f+__expf(-ar)); \
  float an=gn+(BN0)+rg*(hnv+(BN1)); an=fminf(fmaxf(an,-15.f),15.f); \
  float e2=__expf(2.f*an); float nn=(e2-1.f)/(e2+1.f); \
  float hnew=z_*hold+(1.f-z_)*nn;

#define LOADH_SH() \
  { const bf16* hp_=s_h+hcur*1696+l15*104+8*q; \
    _Pragma("unroll") for(int s=0;s<4;++s) aH[s]=*(const bf16x8_t*)(hp_+32*s); }
#define LOADH_HBK() \
  { const bf16* hp_=s_hbk+bcur*1696+l15*104+8*q; \
    _Pragma("unroll") for(int s=0;s<4;++s) aH[s]=*(const bf16x8_t*)(hp_+32*s); }
#define LOADX_RING(RS) \
  { const bf16* xp_=s_ring+(size_t)((RS)*16+l15)*120+8*q; \
    aX0=*(const bf16x8_t*)(xp_); aX1=*(const bf16x8_t*)(xp_+32); }

#define MM_FWD() \
  if (act){ _Pragma("unroll") for (int e=0;e<3;++e){ \
    accB[e]=(f32x4_t){0,0,0,0}; accA[e]=(f32x4_t){0,0,0,0}; \
    _Pragma("unroll") for (int s=0;s<4;++s) accB[e]=MFMA16(aH[s],rUf[e][s],accB[e]); \
    const unsigned char* fb_=smem+WFF_LDS+(((wv*3+e)*2)<<10)+lane*16; \
    accA[e]=MFMA16(aX0,*(const bf16x8_t*)(fb_),accA[e]); \
    accA[e]=MFMA16(aX1,*(const bf16x8_t*)(fb_+1024),accA[e]); } }

#define MM_BWD_X() \
  if (act){ _Pragma("unroll") for (int e=0;e<3;++e){ \
    accB[e]=(f32x4_t){0,0,0,0}; accA[e]=(f32x4_t){0,0,0,0}; \
    _Pragma("unroll") for (int s=0;s<4;++s) accB[e]=MFMA16(aH[s],rUb[e][s],accB[e]); \
    const unsigned char* fb_=smem+WBF_LDS+(((wv*3+e)*2)<<10)+lane*16; \
    accA[e]=MFMA16(aX0,*(const bf16x8_t*)(fb_),accA[e]); \
    accA[e]=MFMA16(aX1,*(const bf16x8_t*)(fb_+1024),accA[e]); } }

#define MM_BWD_NOX() \
  if (act){ _Pragma("unroll") for (int e=0;e<3;++e){ \
    accB[e]=(f32x4_t){0,0,0,0}; \
    _Pragma("unroll") for (int s=0;s<4;++s) accB[e]=MFMA16(aH[s],rUb[e][s],accB[e]); } }

#define FWD_GATE() \
  { bf16* wr_=s_h+(hcur^1)*1696; \
    if (jv){ \
      _Pragma("unroll") for (int i=0;i<4;++i){ const int r_=4*q+i; \
        const float gz=accA[0][i]+W64f[0], gr=accA[1][i]+W64f[1], gn=accA[2][i]+W64f[2]; \
        const float hz=accB[0][i],hr=accB[1][i],hnv=accB[2][i]; \
        const float hold=h_reg[i]; \
        GRU_MATH(Bzf,Brf,Bn0f,Bn1f) \
        h_reg[i]=hnew; wr_[r_*104+j]=__float2bfloat16(hnew); } } \
    hcur^=1; BAR(); }

#define CH_GATE_X(HOLDE, SP) \
  { bf16* wr_=s_hbk+(bcur^1)*1696; \
    if (jv){ \
      _Pragma("unroll") for (int i=0;i<4;++i){ const int r_=4*q+i; \
        const float gz=accA[0][i]+W64b[0], gr=accA[1][i]+W64b[1], gn=accA[2][i]+W64b[2]; \
        const float hz=accB[0][i],hr=accB[1][i],hnv=accB[2][i]; \
        const float hold=(HOLDE); \
        GRU_MATH(Bzb,Brb,Bn0b,Bn1b) \
        hb_reg[i]=hnew; wr_[r_*104+j]=__float2bfloat16(hnew); \
        if ((SP)>=0) s_spl[(size_t)(SP)*1664+r_*104+j]=__float2bfloat16(hnew); } } \
    bcur^=1; BAR(); }

#define CH_GATE_NOX(HOLDE, SP) \
  { bf16* wr_=s_hbk+(bcur^1)*1696; \
    if (jv){ \
      _Pragma("unroll") for (int i=0;i<4;++i){ const int r_=4*q+i; \
        const float gz=0.f, gr=0.f, gn=0.f; \
        const float hz=accB[0][i],hr=accB[1][i],hnv=accB[2][i]; \
        const float hold=(HOLDE); \
        GRU_MATH(Bzb,Brb,Bn0b,Bn1b) \
        hb_reg[i]=hnew; wr_[r_*104+j]=__float2bfloat16(hnew); \
        if ((SP)>=0) s_spl[(size_t)(SP)*1664+r_*104+j]=__float2bfloat16(hnew); } } \
    bcur^=1; BAR(); }

#define FF_OP(RS)       { bf16x8_t aH[4]; bf16x8_t aX0,aX1; f32x4_t accB[3],accA[3]; \
                          if (act){ LOADH_SH() LOADX_RING(RS) } MM_FWD() FWD_GATE() }
#define FA_OP()         { bf16x8_t aH[4]; bf16x8_t aX0,aX1; f32x4_t accB[3],accA[3]; \
                          if (act){ LOADH_SH() aX0=pX[0]; aX1=pX[1]; } MM_FWD() FWD_GATE() }
#define CH_CUR(SP)      { bf16x8_t aH[4]; f32x4_t accB[3]; \
                          if (act){ LOADH_HBK() } MM_BWD_NOX() CH_GATE_NOX(hb_reg[i], SP) }
#define CH_CURX(RS,SP)  { bf16x8_t aH[4]; bf16x8_t aX0,aX1; f32x4_t accB[3],accA[3]; \
                          if (act){ LOADH_HBK() LOADX_RING(RS) } MM_BWD_X() CH_GATE_X(hb_reg[i], SP) }
#define CH_SAVX(RS,SP)  { bf16x8_t aH[4]; bf16x8_t aX0,aX1; f32x4_t accB[3],accA[3]; \
                          if (act){ _Pragma("unroll") for(int s=0;s<4;++s) aH[s]=pHB[s]; \
                                    LOADX_RING(RS) } MM_BWD_X() CH_GATE_X(pHold[i], SP) }
#define CH_SPLX(SI,RS,SP) { bf16x8_t aH[4]; bf16x8_t aX0,aX1; f32x4_t accB[3],accA[3]; \
                          if (act){ const bf16* hp_=s_spl+(size_t)(SI)*1664+l15*104+8*q; \
                            _Pragma("unroll") for(int s=0;s<4;++s) aH[s]=*(const bf16x8_t*)(hp_+32*s); \
                            LOADX_RING(RS) } MM_BWD_X() \
                          CH_GATE_X(__bfloat162float(s_spl[(size_t)(SI)*1664+r_*104+j]), SP) }

#define DEC_COMMON(LVL, DT) \
  const int t_=ba+(DT); \
  bf16x8_t mw0_, mw1_; bf16x8_t aG[8]; \
  if (wv<4){ \
    const bf16* bpM_=MW+((size_t)((LVL)*64+c16))*64+8*q; \
    mw0_=*(const bf16x8_t*)(bpM_); mw1_=*(const bf16x8_t*)(bpM_+32); \
    const bf16* hp_=s_h+hcur*1696+l15*104+8*q; \
    _Pragma("unroll") for(int s=0;s<4;++s) aG[s]=*(const bf16x8_t*)(hp_+32*s); }

#define DEC_TAIL(LVL, SLOT) \
  if (wv<4){ const bf16* bp_=dW+((size_t)((LVL)*64+c16))*256+8*q; \
    f32x4_t a1=(f32x4_t){0,0,0,0},a2=(f32x4_t){0,0,0,0}; \
    _Pragma("unroll") for(int s=0;s<8;s+=2){ \
      a1=MFMA16(aG[s],  *(const bf16x8_t*)(bp_+32*s),    a1); \
      a2=MFMA16(aG[s+1],*(const bf16x8_t*)(bp_+32*(s+1)),a2); } \
    const float db_=db_l[(LVL)]; \
    _Pragma("unroll") for(int i=0;i<4;++i){ float v_=fmaxf(a1[i]+a2[i]+db_,0.f); s_dec[(4*q+i)*72+c16]=__float2bfloat16(v_);} } \
  BAR(); \
  if (wv<4){ \
    bf16x8_t aD0=*(const bf16x8_t*)(s_dec+l15*72+8*q), aD1=*(const bf16x8_t*)(s_dec+l15*72+8*q+32); \
    f32x4_t am=(f32x4_t){0,0,0,0}; am=MFMA16(aD0,mw0_,am); am=MFMA16(aD1,mw1_,am); \
    const float mb_=mb_l[(LVL)]; \
    _Pragma("unroll") for(int i=0;i<4;++i){ const int r_=4*q+i; const size_t b_=(size_t)wg*16+r_; \
      const float m_=am[i]+mb_; \
      s_ring[(size_t)((SLOT)*16+r_)*120+c16]=__float2bfloat16(m_); \
      if (c16>=1) out[(b_*64+(c16-1))*256+t_]=m_; else out[(b_*64+63)*256+t_]=1.0f; } } \
  BAR();

#define DEC_SAV(LVL,DT,SLOT) { DEC_COMMON(LVL,DT) \
  if (wv<4){ _Pragma("unroll") for(int s=0;s<4;++s) aG[4+s]=rS16[s]; } \
  DEC_TAIL(LVL,SLOT) }
#define DEC_CUR(LVL,DT,SLOT) { DEC_COMMON(LVL,DT) \
  if (wv<4){ const bf16* hp_=s_hbk+bcur*1696+l15*104+8*q; \
    _Pragma("unroll") for(int s=0;s<4;++s) aG[4+s]=*(const bf16x8_t*)(hp_+32*s); } \
  DEC_TAIL(LVL,SLOT) }
#define DEC_SPL(LVL,DT,SLOT,SI) { DEC_COMMON(LVL,DT) \
  if (wv<4){ const bf16* hp_=s_spl+(size_t)(SI)*1664+l15*104+8*q; \
    _Pragma("unroll") for(int s=0;s<4;++s) aG[4+s]=*(const bf16x8_t*)(hp_+32*s); } \
  DEC_TAIL(LVL,SLOT) }

#define PREF_RS16(SLOT) if (wv<4){ \
  const bf16* ps_=sav+(size_t)(wg*64+(SLOT))*2048+l15*128+8*q; \
  _Pragma("unroll") for(int s=0;s<4;++s) rS16[s]=*(const bf16x8_t*)(ps_+32*s); }
#define PREF_HB(SLOT) if (act){ \
  const bf16* ps_=sav+(size_t)(wg*64+(SLOT))*2048+l15*128+8*q; \
  _Pragma("unroll") for(int s=0;s<4;++s) pHB[s]=*(const bf16x8_t*)(ps_+32*s); \
  if (j<100){ const bf16* ph_=sav+(size_t)(wg*64+(SLOT))*2048; \
    _Pragma("unroll") for(int i=0;i<4;++i) pHold[i]=__bfloat162float(ph_[(4*q+i)*128+j]); } }
#define PREF_PX(T) if (act){ \
  const bf16* px_=xT+(((size_t)wg*256+(size_t)(T))*16+l15)*96+8*q; \
  pX[0]=*(const bf16x8_t*)(px_); pX[1]=*(const bf16x8_t*)(px_+32); }

  // prologue: prefetch sav frags for block 0, then FA(0) (pX holds X(t=0))
  PREF_RS16(3)
  PREF_HB(0)
  FA_OP()

  #pragma unroll 1
  for (int blk=0; blk<16; ++blk){
    const int ba=16*blk;
    const int sb=4*blk;    // sav slots: s9=sb, s13=sb+1, s15=sb+2, s16=sb+3
    DEC_SAV(3, 8, 0)
    CH_SAVX(0, 0)
    CH_CUR(1)
    CH_CUR(-1)
    CH_CUR(-1)
    DEC_SPL(2, 4, 4, 0)
    CH_CURX(4, 2)
    CH_CUR(-1)
    DEC_SPL(1, 2, 2, 2)
    CH_CURX(2, -1)
    DEC_CUR(0, 1, 1)
    FF_OP(1) FF_OP(2)
    DEC_SPL(0, 3, 3, 2)
    FF_OP(3) FF_OP(4)
    DEC_SPL(1, 6, 6, 0)
    CH_SPLX(1, 6, -1)
    DEC_CUR(0, 5, 5)
    FF_OP(5) FF_OP(6)
    DEC_SPL(0, 7, 7, 0)
    FF_OP(7) FF_OP(0)
    PREF_HB(sb+1)
    DEC_SAV(2, 12, 4)
    CH_SAVX(4, 3)
    CH_CUR(-1)
    DEC_SPL(1, 10, 2, 3)
    CH_CURX(2, -1)
    DEC_CUR(0, 9, 1)
    FF_OP(1) FF_OP(2)
    DEC_SPL(0, 11, 3, 3)
    FF_OP(3) FF_OP(4)
    PREF_HB(sb+2)
    DEC_SAV(1, 14, 6)
    CH_SAVX(6, -1)
    DEC_CUR(0, 13, 5)
    FF_OP(5) FF_OP(6)
    DEC_SAV(0, 15, 7)
    if (blk<15){
      PREF_RS16(sb+7)
      PREF_HB(sb+4)
      PREF_PX(ba+16)
      FF_OP(7)
      FA_OP()
    }
  }
}

// ---------------- launch ----------------
extern "C" void kernel_launch(void* const* d_in, const int* in_sizes, int n_in,
                              void* d_out, int out_size, void* d_ws, size_t ws_size,
                              hipStream_t stream){
  (void)out_size;
  const float *a=nullptr,*gru_W=nullptr,*gru_U=nullptr,*gru_b=nullptr,*bgru_W=nullptr,
              *bgru_U=nullptr,*bgru_b=nullptr,*dec_W=nullptr,*dec_b=nullptr,
              *mean_W=nullptr,*mean_b=nullptr;
  int nU=0, nb6=0;
  for (int i=0;i<n_in;++i){
    const float* p=(const float*)d_in[i]; int s=in_sizes[i];
    if      (s==25165824) a=p;
    else if (s==19200)    gru_W=p;
    else if (s==19500)    bgru_W=p;
    else if (s==30000)    { if(nU++==0) gru_U=p; else bgru_U=p; }
    else if (s==600)      { if(nb6++==0) gru_b=p; else bgru_b=p; }
    else if (s==40000)    dec_W=p;
    else if (s==200)      dec_b=p;
    else if (s==12800)    mean_W=p;
    else if (s==256)      mean_b=p;
  }
  if (!a||!gru_W||!gru_U||!gru_b||!bgru_W||!bgru_U||!bgru_b||!dec_W||!dec_b||!mean_W||!mean_b){
    a=(const float*)d_in[0]; gru_W=(const float*)d_in[1]; gru_U=(const float*)d_in[2];
    gru_b=(const float*)d_in[3]; bgru_W=(const float*)d_in[4]; bgru_U=(const float*)d_in[5];
    bgru_b=(const float*)d_in[6]; dec_W=(const float*)d_in[7]; dec_b=(const float*)d_in[8];
    mean_W=(const float*)d_in[9]; mean_b=(const float*)d_in[10];
  }
  unsigned char* ws = (unsigned char*)d_ws;
  float* out = (float*)d_out;

  k_obs  <<<512,  64, 0, stream>>>(a, out);
  if (ws_size < WS_NEED) return;

  k_sz   <<<2048, 256, 0, stream>>>((uint4*)(ws+SAV_OFF));
  k_xt   <<<512, 256, 0, stream>>>(a, (bf16*)(ws+XT_OFF));
  k_wt   <<<336, 128, 0, stream>>>(gru_U, bgru_U, gru_W, bgru_W,
                                   (bf16*)(ws+UF_OFF), (bf16*)(ws+UB_OFF),
                                   (bf16*)(ws+WF_OFF), (bf16*)(ws+WB_OFF));
  k_wbf  <<<84,   64, 0, stream>>>((const bf16*)(ws+WB_OFF), (const bf16*)(ws+WF_OFF),
                                   (uint4*)(ws+WBF_OFF));
  k_decw <<<256, 256, 0, stream>>>(dec_W, (bf16*)(ws+DW_OFF));
  k_mw   <<<256,  64, 0, stream>>>(mean_W, (bf16*)(ws+MW_OFF));
  k_consts<<<1,  256, 0, stream>>>(gru_b, bgru_b, mean_b, dec_b, (float*)(ws+CST_OFF));
  naomi_main<<<32, 512, 0, stream>>>(ws, out);
}